// Round 1
// baseline (52.063 us; speedup 1.0000x reference)
//
#include <hip/hip_runtime.h>
#include <math.h>

// Problem geometry (fixed by reference setup_inputs)
#define B_ 32
#define S_ 512
#define D_ 1024
#define EPS_ 1e-8f
#define BETA_ 0.1
#define NCH 16           // S-chunks for deterministic column-sum partials
#define TCH (S_ / NCH)   // 32 timesteps per chunk

// ---------- helpers ----------

// mask layout flag: 0 = int32 (0/1), 1 = byte bool, 2 = float32 (0/1.0)
__device__ __forceinline__ float mask_val(const void* mp, int lay, int idx) {
  if (lay == 1) return ((const unsigned char*)mp)[idx] ? 1.0f : 0.0f;
  if (lay == 2) return (((const float*)mp)[idx] != 0.0f) ? 1.0f : 0.0f;
  return ((const int*)mp)[idx] ? 1.0f : 0.0f;
}

__device__ __forceinline__ float wave_sum_f(float v) {
#pragma unroll
  for (int off = 32; off > 0; off >>= 1) v += __shfl_down(v, off);
  return v;
}
__device__ __forceinline__ double wave_sum_d(double v) {
#pragma unroll
  for (int off = 32; off > 0; off >>= 1) v += __shfl_down(v, off);
  return v;
}

// ---------- kernel 0: classify mask memory layout ----------
// Reads the first B_*D_/4 32-bit words (= full buffer if byte-bool layout).
// int32 0/1 mask  -> all words in {0,1}
// float 0/1.0     -> words in {0, 0x3F800000}
// byte bool       -> packed words like 0x00010001 (values >1, != 0x3F800000)
__global__ void detect_kernel(const unsigned int* __restrict__ w, int nwords,
                              int* __restrict__ flag) {
  __shared__ int c_odd, c_f;
  if (threadIdx.x == 0) { c_odd = 0; c_f = 0; }
  __syncthreads();
  int lodd = 0, lf = 0;
  for (int i = threadIdx.x; i < nwords; i += blockDim.x) {
    unsigned int v = w[i];
    if (v == 0x3F800000u) lf++;
    else if (v > 1u) lodd++;
  }
  if (lodd) atomicAdd(&c_odd, lodd);
  if (lf) atomicAdd(&c_f, lf);
  __syncthreads();
  if (threadIdx.x == 0) *flag = (c_odd > 0) ? 1 : ((c_f > 0) ? 2 : 0);
}

// ---------- kernel 1: per-(b,t) masked squared norms ----------
// One 256-thread block per row; each thread loads one float4 (coalesced 4KB/block).
__global__ __launch_bounds__(256) void norms_kernel(
    const float* __restrict__ fix, const void* __restrict__ mask,
    const int* __restrict__ flag, float* __restrict__ inv_n,
    float* __restrict__ simtt) {
  const int blk = blockIdx.x;   // = b*S_ + t
  const int b = blk >> 9;       // S_ = 512
  const int tid = threadIdx.x;
  const int lay = *flag;
  const float4 v = ((const float4*)(fix + (size_t)blk * D_))[tid];
  const int mbase = b * D_ + tid * 4;
  float ssq = v.x * v.x * mask_val(mask, lay, mbase + 0)
            + v.y * v.y * mask_val(mask, lay, mbase + 1)
            + v.z * v.z * mask_val(mask, lay, mbase + 2)
            + v.w * v.w * mask_val(mask, lay, mbase + 3);
  ssq = wave_sum_f(ssq);
  __shared__ float red[4];
  if ((tid & 63) == 0) red[tid >> 6] = ssq;
  __syncthreads();
  if (tid == 0) {
    const float s = red[0] + red[1] + red[2] + red[3];
    const float n = fmaxf(sqrtf(fmaxf(s, 0.0f)), EPS_);
    const float inv = 1.0f / n;
    inv_n[blk] = inv;
    simtt[blk] = s * inv * inv;   // == sim[t,t] (1.0 normally, 0 if fully masked)
  }
}

// ---------- kernel 2: column sums y_partial[ch][b][d] = sum_{t in chunk} x/n_t ----------
// Block covers all of D via float4 (256 threads * 4 = 1024); coalesced 4KB per t-step.
// Mask is NOT applied here (applied once in the reduction; m is t-independent & binary).
__global__ __launch_bounds__(256) void colsum_kernel(
    const float* __restrict__ fix, const float* __restrict__ inv_n,
    float* __restrict__ part) {
  const int b = blockIdx.x / NCH;
  const int ch = blockIdx.x % NCH;
  const int tid = threadIdx.x;
  const float4* base = (const float4*)(fix + ((size_t)b * S_ + (size_t)ch * TCH) * D_);
  const float* inv = inv_n + b * S_ + ch * TCH;
  float4 acc = make_float4(0.0f, 0.0f, 0.0f, 0.0f);
#pragma unroll 8
  for (int t = 0; t < TCH; ++t) {
    const float w = inv[t];
    const float4 v = base[(size_t)t * (D_ / 4) + tid];
    acc.x += v.x * w; acc.y += v.y * w; acc.z += v.z * w; acc.w += v.w * w;
  }
  ((float4*)(part + (size_t)ch * (B_ * D_) + (size_t)b * D_))[tid] = acc;
}

// ---------- kernel 3a: deterministic reduction to 128 block partials ----------
// gid in [0, B_*D_): combine NCH chunk partials, mask, square -> "full" sum.
// gid in [0, B_*S_): also accumulate diagonal sims -> "diag" sum.
__global__ __launch_bounds__(256) void reduce_kernel(
    const float* __restrict__ part, const void* __restrict__ mask,
    const int* __restrict__ flag, const float* __restrict__ simtt,
    double* __restrict__ blkout) {
  const int tid = threadIdx.x;
  const int gid = blockIdx.x * 256 + tid;   // 0 .. 32767
  const int lay = *flag;
  float s = 0.0f;
#pragma unroll
  for (int c = 0; c < NCH; ++c) s += part[c * (B_ * D_) + gid];
  const float sm = s * mask_val(mask, lay, gid);
  double full = (double)sm * (double)sm;
  double diag = (gid < B_ * S_) ? (double)simtt[gid] : 0.0;
  full = wave_sum_d(full);
  diag = wave_sum_d(diag);
  __shared__ double redf[4], redd[4];
  if ((tid & 63) == 0) { redf[tid >> 6] = full; redd[tid >> 6] = diag; }
  __syncthreads();
  if (tid == 0) {
    blkout[blockIdx.x * 2 + 0] = redf[0] + redf[1] + redf[2] + redf[3];
    blkout[blockIdx.x * 2 + 1] = redd[0] + redd[1] + redd[2] + redd[3];
  }
}

// ---------- kernel 3b: final scalar ----------
__global__ __launch_bounds__(128) void final_kernel(
    const double* __restrict__ blkout, float* __restrict__ out) {
  const int tid = threadIdx.x;   // 128 threads <- 128 block partials
  double f = blkout[tid * 2 + 0];
  double g = blkout[tid * 2 + 1];
  f = wave_sum_d(f);
  g = wave_sum_d(g);
  __shared__ double rf[2], rg[2];
  if ((tid & 63) == 0) { rf[tid >> 6] = f; rg[tid >> 6] = g; }
  __syncthreads();
  if (tid == 0) {
    const double F = rf[0] + rf[1];
    const double G = rg[0] + rg[1];
    const double total = 0.5 * (F - G);                       // strict upper triangle
    const double count = (double)B_ * S_ * (S_ - 1) / 2.0;    // 4,186,112
    const double avg = total / count;
    const double val = -log(1.0 - 0.5 * (avg + 1.0)) * BETA_;
    out[0] = (float)val;
  }
}

extern "C" void kernel_launch(void* const* d_in, const int* in_sizes, int n_in,
                              void* d_out, int out_size, void* d_ws, size_t ws_size,
                              hipStream_t stream) {
  const float* fix = (const float*)d_in[0];
  const void* mask = d_in[1];
  char* ws = (char*)d_ws;

  // workspace layout (all 256B-aligned)
  int* flag      = (int*)ws;                                       // 4 B
  float* inv_n   = (float*)(ws + 256);                             // 16384 f32
  float* simtt   = (float*)(ws + 256 + 65536);                     // 16384 f32
  float* part    = (float*)(ws + 256 + 2 * 65536);                 // NCH*B*D f32 = 2 MiB
  double* blkout = (double*)(ws + 256 + 2 * 65536 +
                             (size_t)NCH * B_ * D_ * sizeof(float)); // 128*2 f64

  float* out = (float*)d_out;

  detect_kernel<<<1, 256, 0, stream>>>((const unsigned int*)mask, (B_ * D_) / 4, flag);
  norms_kernel<<<B_ * S_, 256, 0, stream>>>(fix, mask, flag, inv_n, simtt);
  colsum_kernel<<<B_ * NCH, 256, 0, stream>>>(fix, inv_n, part);
  reduce_kernel<<<(B_ * D_) / 256, 256, 0, stream>>>(part, mask, flag, simtt, blkout);
  final_kernel<<<1, 128, 0, stream>>>(blkout, out);
}

// Round 2
// 22.932 us; speedup vs baseline: 2.2703x; 2.2703x over previous
//
#include <hip/hip_runtime.h>
#include <math.h>

// Problem geometry (fixed by reference setup_inputs)
#define B_ 32
#define S_ 512
#define D_ 1024
#define EPS_ 1e-8f
#define BETA_ 0.1
#define NCH 32           // S-chunks per batch (grid = B*NCH = 1024 blocks)
#define TCH (S_ / NCH)   // 16 timesteps per chunk

// ---------- helpers ----------

// mask layout flag: 0 = int32 (0/1), 1 = byte bool, 2 = float32 (0/1.0)
__device__ __forceinline__ float mask_val(const void* mp, int lay, int idx) {
  if (lay == 1) return ((const unsigned char*)mp)[idx] ? 1.0f : 0.0f;
  if (lay == 2) return (((const float*)mp)[idx] != 0.0f) ? 1.0f : 0.0f;
  return ((const int*)mp)[idx] ? 1.0f : 0.0f;
}

__device__ __forceinline__ float wave_sum_f(float v) {
#pragma unroll
  for (int off = 32; off > 0; off >>= 1) v += __shfl_down(v, off);
  return v;
}
__device__ __forceinline__ double wave_sum_d(double v) {
#pragma unroll
  for (int off = 32; off > 0; off >>= 1) v += __shfl_down(v, off);
  return v;
}

// In-block mask-layout detection from the first 1 KB of the mask buffer
// (uniform across blocks; L2-hot). int32 0/1 -> words in {0,1};
// float 0/1.0 -> words contain 0x3F800000; packed byte bool -> words > 1.
__device__ __forceinline__ int detect_layout(const void* mask, int tid,
                                             int* sflags) {
  if (tid == 0) *sflags = 0;
  __syncthreads();
  unsigned int w = ((const unsigned int*)mask)[tid & 255];
  int f = 0;
  if (w == 0x3F800000u) f = 2;
  else if (w > 1u) f = 1;
  if (f && (tid < 256)) atomicOr(sflags, f);
  __syncthreads();
  const int fl = *sflags;
  return (fl & 1) ? 1 : ((fl & 2) ? 2 : 0);
}

// ---------- kernel 1 (fused): single pass over fix_outputs ----------
// One block per (b, S-chunk). Each thread owns 4 feature dims (float4).
// Per row t: block-reduce masked ssq -> inv_n -> weight row into register
// column accumulator. Input is read exactly once.
__global__ __launch_bounds__(256) void fused_kernel(
    const float* __restrict__ fix, const void* __restrict__ mask,
    float* __restrict__ part, float* __restrict__ diagpart) {
  const int b = blockIdx.x / NCH;
  const int ch = blockIdx.x % NCH;
  const int tid = threadIdx.x;

  __shared__ int sflags;
  const int lay = detect_layout(mask, tid, &sflags);

  // this thread's mask for its 4 feature dims (constant over t)
  const int mb = b * D_ + tid * 4;
  float4 m4;
  m4.x = mask_val(mask, lay, mb + 0);
  m4.y = mask_val(mask, lay, mb + 1);
  m4.z = mask_val(mask, lay, mb + 2);
  m4.w = mask_val(mask, lay, mb + 3);

  const float4* base =
      (const float4*)(fix + ((size_t)b * S_ + (size_t)ch * TCH) * D_);

  __shared__ float red[4];
  float4 acc = make_float4(0.0f, 0.0f, 0.0f, 0.0f);
  float diag = 0.0f;

  float4 v = base[tid];  // prefetch row 0
  for (int t = 0; t < TCH; ++t) {
    float4 vn = make_float4(0.0f, 0.0f, 0.0f, 0.0f);
    if (t + 1 < TCH) vn = base[(size_t)(t + 1) * (D_ / 4) + tid];  // prefetch

    float ssq = v.x * v.x * m4.x + v.y * v.y * m4.y +
                v.z * v.z * m4.z + v.w * v.w * m4.w;
    ssq = wave_sum_f(ssq);
    if ((tid & 63) == 0) red[tid >> 6] = ssq;
    __syncthreads();
    const float s = red[0] + red[1] + red[2] + red[3];
    const float inv = 1.0f / fmaxf(sqrtf(fmaxf(s, 0.0f)), EPS_);
    acc.x += v.x * inv; acc.y += v.y * inv;
    acc.z += v.z * inv; acc.w += v.w * inv;
    diag += s * inv * inv;  // sim[t,t] (1.0 normally, 0 if fully masked row)
    v = vn;
    __syncthreads();  // protect red[] reuse next iteration
  }

  // unmasked column partials (mask applied once in reduce, m binary & t-indep)
  ((float4*)(part + (size_t)ch * (B_ * D_) + (size_t)b * D_))[tid] = acc;
  if (tid == 0) diagpart[blockIdx.x] = diag;  // same value in all threads
}

// ---------- kernel 2: deterministic reduction to 128 block partials ----------
__global__ __launch_bounds__(256) void reduce_kernel(
    const float* __restrict__ part, const void* __restrict__ mask,
    const float* __restrict__ diagpart, double* __restrict__ blkout) {
  const int tid = threadIdx.x;
  const int gid = blockIdx.x * 256 + tid;  // 0 .. B*D-1 (32767)

  __shared__ int sflags;
  const int lay = detect_layout(mask, tid, &sflags);

  float s = 0.0f;
#pragma unroll
  for (int c = 0; c < NCH; ++c) s += part[c * (B_ * D_) + gid];
  const float sm = s * mask_val(mask, lay, gid);
  double full = (double)sm * (double)sm;
  full = wave_sum_d(full);
  __shared__ double redf[4];
  if ((tid & 63) == 0) redf[tid >> 6] = full;
  __syncthreads();
  if (tid == 0) {
    // each block also owns 8 of the 1024 diag partials (fixed order)
    double dg = 0.0;
#pragma unroll
    for (int k = 0; k < 8; ++k) dg += (double)diagpart[blockIdx.x * 8 + k];
    blkout[blockIdx.x * 2 + 0] = redf[0] + redf[1] + redf[2] + redf[3];
    blkout[blockIdx.x * 2 + 1] = dg;
  }
}

// ---------- kernel 3: final scalar ----------
__global__ __launch_bounds__(128) void final_kernel(
    const double* __restrict__ blkout, float* __restrict__ out) {
  const int tid = threadIdx.x;  // 128 threads <- 128 block partials
  double f = blkout[tid * 2 + 0];
  double g = blkout[tid * 2 + 1];
  f = wave_sum_d(f);
  g = wave_sum_d(g);
  __shared__ double rf[2], rg[2];
  if ((tid & 63) == 0) { rf[tid >> 6] = f; rg[tid >> 6] = g; }
  __syncthreads();
  if (tid == 0) {
    const double F = rf[0] + rf[1];   // sum_b ||sum_t x_hat_t||^2
    const double G = rg[0] + rg[1];   // sum of diagonal sims
    const double total = 0.5 * (F - G);                     // strict upper tri
    const double count = (double)B_ * S_ * (S_ - 1) / 2.0;  // 4,186,112
    const double avg = total / count;
    const double val = -log(1.0 - 0.5 * (avg + 1.0)) * BETA_;
    out[0] = (float)val;
  }
}

extern "C" void kernel_launch(void* const* d_in, const int* in_sizes, int n_in,
                              void* d_out, int out_size, void* d_ws, size_t ws_size,
                              hipStream_t stream) {
  const float* fix = (const float*)d_in[0];
  const void* mask = d_in[1];
  char* ws = (char*)d_ws;

  // workspace layout (256B-aligned)
  float* part     = (float*)ws;                                   // NCH*B*D f32 = 4 MiB
  float* diagpart = (float*)(ws + (size_t)NCH * B_ * D_ * 4);     // 1024 f32
  double* blkout  = (double*)(ws + (size_t)NCH * B_ * D_ * 4 + 8192); // 256 f64

  float* out = (float*)d_out;

  fused_kernel<<<B_ * NCH, 256, 0, stream>>>(fix, mask, part, diagpart);
  reduce_kernel<<<(B_ * D_) / 256, 256, 0, stream>>>(part, mask, diagpart, blkout);
  final_kernel<<<1, 128, 0, stream>>>(blkout, out);
}